// Round 1
// 449.112 us; speedup vs baseline: 1.0052x; 1.0052x over previous
//
#include <hip/hip_runtime.h>

typedef __attribute__((ext_vector_type(8))) short short8;
typedef __attribute__((ext_vector_type(4))) float floatx4;
typedef unsigned short ushort_t;
typedef unsigned int uint32;

// ---------- helpers ----------

__device__ __forceinline__ uint32 f2bf_bits(float f) {
  uint32 u = __builtin_bit_cast(uint32, f);
  u += 0x7fffu + ((u >> 16) & 1u);   // round-to-nearest-even
  return u >> 16;
}

__device__ __forceinline__ float tanh_fast(float x) {
  float e = __expf(2.0f * x);
  return 1.0f - 2.0f * __builtin_amdgcn_rcpf(e + 1.0f);
}

#define MFMA16(a, b, c) __builtin_amdgcn_mfma_f32_16x16x32_bf16((a), (b), (c), 0, 0, 0)

// lgkm-only barrier: __syncthreads() drains vmcnt(0) (kills in-flight HBM/L2
// prefetch every group). All cross-wave dataflow here is via LDS, so
// lgkmcnt(0) + s_barrier is sufficient for correctness.
#define BAR_LGKM() asm volatile("s_waitcnt lgkmcnt(0)\n\ts_barrier" ::: "memory")

// ---------- prep: fold weights, cast to bf16, pre-transpose to [n][k] ----------
// ws layout:
//   Wtm      [16][128 o][256 i] bf16   @ 0      (W_mid * w_inp, transposed)
//   Wtr      [256 o][2048 k]    bf16   @ 1 MB   (W_root transposed)
//   bias_eff [16][128]          f32    @ 2 MB   (b_mid + sum_i pbias*W_mid)
//   part     [2][16384][256]    f32    @ 4 MB   (split-K partials, if ws fits)
//
// v2: LDS 32x32 tile transposes (coalesced reads AND writes; old version wrote
// 2 B per 64 B cacheline) + parallel coalesced bias reduction.

__global__ __launch_bounds__(256) void prep(const float* __restrict__ w_inp,
                                            const float* __restrict__ pbias,
                                            const float* __restrict__ W_mid,
                                            const float* __restrict__ b_mid,
                                            const float* __restrict__ W_root,
                                            ushort_t* __restrict__ Wtm,
                                            ushort_t* __restrict__ Wtr,
                                            float* __restrict__ bias_eff) {
  __shared__ float tl[32][33];
  __shared__ float red[256];
  const int b = blockIdx.x, t = threadIdx.x;
  const int tx = t & 31, ty = t >> 5;              // ty 0..7

  if (b < 512) {
    // Wtm[g][o][i] = W_mid[g][i][o] * w_inp[g*256+i];  per-g 256x128, 32x32 tiles
    const int g = b >> 5, tile = b & 31;
    const int i0 = (tile >> 2) * 32, o0 = (tile & 3) * 32;
#pragma unroll
    for (int r = 0; r < 4; ++r) {
      const int il = ty * 4 + r;
      tl[il][tx] = W_mid[(g << 15) + (i0 + il) * 128 + o0 + tx] * w_inp[g * 256 + i0 + il];
    }
    __syncthreads();
#pragma unroll
    for (int r = 0; r < 4; ++r) {
      const int orow = ty * 4 + r;
      Wtm[(g << 15) + (o0 + orow) * 256 + i0 + tx] = (ushort_t)f2bf_bits(tl[tx][orow]);
    }
  } else if (b < 1024) {
    // Wtr[o][k] = W_root[k][o];  2048x256, 32x32 tiles
    const int bb = b - 512;
    const int k0 = (bb >> 3) * 32, o0 = (bb & 7) * 32;
#pragma unroll
    for (int r = 0; r < 4; ++r) {
      const int kl = ty * 4 + r;
      tl[kl][tx] = W_root[(k0 + kl) * 256 + o0 + tx];
    }
    __syncthreads();
#pragma unroll
    for (int r = 0; r < 4; ++r) {
      const int orow = ty * 4 + r;
      Wtr[(o0 + orow) * 2048 + k0 + tx] = (ushort_t)f2bf_bits(tl[tx][orow]);
    }
  } else {
    // bias_eff[g][o] = b_mid[g][o] + sum_i pbias[g*4 + i>>6] * W_mid[g][i][o]
    const int g = b - 1024;
    const int o = t & 127, ih = t >> 7;            // ih: which 128-i half
    const float* wp = W_mid + (g << 15) + ih * 128 * 128 + o;
    const float pb0 = pbias[g * 4 + ih * 2];
    const float pb1 = pbias[g * 4 + ih * 2 + 1];
    float s = 0.f;
#pragma unroll 8
    for (int ii = 0; ii < 128; ++ii) s += (ii < 64 ? pb0 : pb1) * wp[ii * 128];
    red[t] = s;
    __syncthreads();
    if (ih == 0) bias_eff[g * 128 + o] = b_mid[g * 128 + o] + red[o] + red[128 + o];
  }
}

// ---------- fused mid+root ----------
// Block: 256 threads (4 waves), 32 batch rows.
// SPLIT: grid 1024, each block does 8 groups (half-K), partials -> ws.
// else : grid  512, 16 groups, writes out directly (+b_root).
//
// Per-group body (2 lgkm-only barriers; issue order is the point):
//   [mb preload(4) + bias(2)]  -> [convert rx(g)->sX]  -> barB
//   mid GEMM (in-loop mb for kk<6 only; no dead tail loads)
//   rb rounds 0,1 preload(8)   -> sched_barrier -> [rx(g+1) prefetch(8)] ->
//   epilogue tanh->sMid        -> barC
//   root GEMM (in-loop rb rounds 2,3 during kk2=0,1; kk2=2,3 pure MFMA)
// No weight load issued after rx within a body => in-order vmcnt retirement
// exposes at most one bounded HBM-latency stall per group, not 3 full drains.

template <bool SPLIT>
__global__ __launch_bounds__(256, 3) void fused(const float* __restrict__ x,
                                                const ushort_t* __restrict__ Wtm,
                                                const ushort_t* __restrict__ Wtr,
                                                const float* __restrict__ bias_eff,
                                                const float* __restrict__ b_root,
                                                float* __restrict__ dst) {
  constexpr int GROUPS = SPLIT ? 8 : 16;

  __shared__ __align__(16) ushort_t sX[32 * 264];   // stride 264: 16B rows, 2-way banks max
  __shared__ __align__(16) ushort_t sMid[32 * 136];

  const int t = threadIdx.x;
  const int lane = t & 63;
  const int wv = __builtin_amdgcn_readfirstlane(t >> 6);
  const int tile = SPLIT ? (int)(blockIdx.x >> 1) : (int)blockIdx.x;
  const int h = SPLIT ? (int)(blockIdx.x & 1) : 0;
  const int G0 = h * 8;
  const int m0 = tile * 32;
  const int l15 = lane & 15;
  const int kh = lane >> 4;          // 0..3

  // x staging: thread t handles row xr = t>>3, float4-slot xq = t&7 (+8 per pass)
  const int xr = t >> 3, xq = t & 7;
  const float* xbase = x + (size_t)(m0 + xr) * 4096 + (size_t)G0 * 256 + xq * 4;
  uint32* sxw = (uint32*)(sX + xr * 264 + xq * 4);

  // A-frag LDS read pointers
  const ushort_t* sxa0 = sX + l15 * 264 + kh * 8;
  const ushort_t* sxa1 = sX + (16 + l15) * 264 + kh * 8;
  const ushort_t* sma0 = sMid + l15 * 136 + kh * 8;
  const ushort_t* sma1 = sMid + (16 + l15) * 136 + kh * 8;

  // B-frag global bases (L2-resident weights)
  const ushort_t* wtm_b0 = Wtm + ((size_t)G0 << 15) + (wv * 32 + l15) * 256 + kh * 8;
  const ushort_t* wtm_b1 = wtm_b0 + 16 * 256;
  const ushort_t* wtr_b = Wtr + (wv * 64 + l15) * 2048 + (size_t)G0 * 128 + kh * 8;

  float4 rx[8];
  floatx4 racc[2][4] = {};

  // prologue: x for local group 0
#pragma unroll
  for (int p = 0; p < 8; ++p) rx[p] = *(const float4*)(xbase + p * 32);

#pragma unroll 1
  for (int g = 0; g < GROUPS; ++g) {
    // ---- body top: this group's first weight loads + biases (issued before
    // anything that will be waited on, so L2 latency is covered by convert) ----
    const ushort_t* wb0 = wtm_b0 + ((size_t)g << 15);
    const ushort_t* wb1 = wtm_b1 + ((size_t)g << 15);
    short8 mb[2][2];
    mb[0][0] = *(const short8*)(wb0);
    mb[0][1] = *(const short8*)(wb1);
    mb[1][0] = *(const short8*)(wb0 + 32);
    mb[1][1] = *(const short8*)(wb1 + 32);
    const float bias0 = bias_eff[(G0 + g) * 128 + wv * 32 + l15];
    const float bias1 = bias_eff[(G0 + g) * 128 + wv * 32 + 16 + l15];

    // ---- convert rx (group g) -> sX, round-half-up + byte-perm pack ----
#pragma unroll
    for (int p = 0; p < 8; ++p) {
      uint32 bx = __builtin_bit_cast(uint32, rx[p].x) + 0x8000u;
      uint32 by = __builtin_bit_cast(uint32, rx[p].y) + 0x8000u;
      uint32 bz = __builtin_bit_cast(uint32, rx[p].z) + 0x8000u;
      uint32 bw = __builtin_bit_cast(uint32, rx[p].w) + 0x8000u;
      uint32 lo = __builtin_amdgcn_perm(by, bx, 0x07060302u);
      uint32 hi = __builtin_amdgcn_perm(bw, bz, 0x07060302u);
      *(uint2*)(sxw + p * 16) = make_uint2(lo, hi);
    }

    BAR_LGKM();  // (B) sX ready; also: all waves past root(g-1) -> sMid WAR safe

    // ---- mid GEMM: 32x128 (wave: 32m x 32n), K=256 ----
    floatx4 macc[2][2] = {};
#pragma unroll
    for (int kk = 0; kk < 8; ++kk) {
      short8 a0 = *(const short8*)(sxa0 + kk * 32);
      short8 a1 = *(const short8*)(sxa1 + kk * 32);
      short8 b0 = mb[kk & 1][0], b1 = mb[kk & 1][1];
      if (kk < 6) {  // no dead tail loads
        mb[kk & 1][0] = *(const short8*)(wb0 + (kk + 2) * 32);
        mb[kk & 1][1] = *(const short8*)(wb1 + (kk + 2) * 32);
      }
      macc[0][0] = MFMA16(a0, b0, macc[0][0]);
      macc[0][1] = MFMA16(a0, b1, macc[0][1]);
      macc[1][0] = MFMA16(a1, b0, macc[1][0]);
      macc[1][1] = MFMA16(a1, b1, macc[1][1]);
    }

    // ---- root B rounds 0,1 preload (8 frags = 32 VGPR) ----
    const ushort_t* wb = wtr_b + g * 128;
    short8 rb[2][4];
#pragma unroll
    for (int ni = 0; ni < 4; ++ni) rb[0][ni] = *(const short8*)(wb + ni * 16 * 2048);
#pragma unroll
    for (int ni = 0; ni < 4; ++ni) rb[1][ni] = *(const short8*)(wb + ni * 16 * 2048 + 32);

    __builtin_amdgcn_sched_barrier(0);  // pin: weights above issue before rx below

    // ---- prefetch next group's x (LAST vmem of the preload phase) ----
    if (g < GROUPS - 1) {
      const float* xn = xbase + (g + 1) * 256;
#pragma unroll
      for (int p = 0; p < 8; ++p) rx[p] = *(const float4*)(xn + p * 32);
    }

    __builtin_amdgcn_sched_barrier(0);  // keep rx issue here (not sunk past epilogue)

    // ---- epilogue: bias + tanh -> sMid (bf16, root-A layout) ----
#pragma unroll
    for (int ni = 0; ni < 2; ++ni) {
      const float bias = ni ? bias1 : bias0;
      const int col = wv * 32 + ni * 16 + l15;
#pragma unroll
      for (int mi = 0; mi < 2; ++mi)
#pragma unroll
        for (int r = 0; r < 4; ++r) {
          const int row = mi * 16 + kh * 4 + r;
          sMid[row * 136 + col] = (ushort_t)f2bf_bits(tanh_fast(macc[mi][ni][r] + bias));
        }
    }

    BAR_LGKM();  // (C) sMid ready

    // ---- root partial: 32x256 (wave: 32m x 64n), K=128, accumulate in racc ----
#pragma unroll
    for (int kk2 = 0; kk2 < 4; ++kk2) {
      short8 a0 = *(const short8*)(sma0 + kk2 * 32);
      short8 a1 = *(const short8*)(sma1 + kk2 * 32);
      short8 b0 = rb[kk2 & 1][0], b1 = rb[kk2 & 1][1];
      short8 b2 = rb[kk2 & 1][2], b3 = rb[kk2 & 1][3];
      if (kk2 < 2) {  // stream rounds 2,3; no dead tail loads
#pragma unroll
        for (int ni = 0; ni < 4; ++ni)
          rb[kk2 & 1][ni] = *(const short8*)(wb + ni * 16 * 2048 + (kk2 + 2) * 32);
      }
      racc[0][0] = MFMA16(a0, b0, racc[0][0]);
      racc[0][1] = MFMA16(a0, b1, racc[0][1]);
      racc[0][2] = MFMA16(a0, b2, racc[0][2]);
      racc[0][3] = MFMA16(a0, b3, racc[0][3]);
      racc[1][0] = MFMA16(a1, b0, racc[1][0]);
      racc[1][1] = MFMA16(a1, b1, racc[1][1]);
      racc[1][2] = MFMA16(a1, b2, racc[1][2]);
      racc[1][3] = MFMA16(a1, b3, racc[1][3]);
    }
  }

  // ---- final store ----
  float* o = SPLIT ? dst + (size_t)h * (16384 * 256) : dst;
#pragma unroll
  for (int ni = 0; ni < 4; ++ni) {
    const int col = wv * 64 + ni * 16 + l15;
    const float br = SPLIT ? 0.0f : b_root[col];
#pragma unroll
    for (int mi = 0; mi < 2; ++mi)
#pragma unroll
      for (int r = 0; r < 4; ++r) {
        const int row = m0 + mi * 16 + kh * 4 + r;
        o[(size_t)row * 256 + col] = racc[mi][ni][r] + br;
      }
  }
}

// ---------- split-K reduce: out = p0 + p1 + b_root ----------

__global__ __launch_bounds__(256) void reducek(const float* __restrict__ part,
                                               const float* __restrict__ b_root,
                                               float* __restrict__ out) {
  const int i = blockIdx.x * 256 + threadIdx.x;   // float4 index, 1,048,576 total
  float4 a = ((const float4*)part)[i];
  float4 c = ((const float4*)(part + (size_t)16384 * 256))[i];
  float4 br = ((const float4*)b_root)[i & 63];
  float4 r;
  r.x = a.x + c.x + br.x;
  r.y = a.y + c.y + br.y;
  r.z = a.z + c.z + br.z;
  r.w = a.w + c.w + br.w;
  ((float4*)out)[i] = r;
}

// ---------- launch ----------

extern "C" void kernel_launch(void* const* d_in, const int* in_sizes, int n_in,
                              void* d_out, int out_size, void* d_ws, size_t ws_size,
                              hipStream_t stream) {
  const float* x      = (const float*)d_in[0];
  const float* w_inp  = (const float*)d_in[1];
  const float* pbias  = (const float*)d_in[2];
  const float* W_mid  = (const float*)d_in[3];
  const float* b_mid  = (const float*)d_in[4];
  const float* W_root = (const float*)d_in[5];
  const float* b_root = (const float*)d_in[6];
  float* out = (float*)d_out;

  char* ws = (char*)d_ws;
  ushort_t* Wtm      = (ushort_t*)(ws);
  ushort_t* Wtr      = (ushort_t*)(ws + (1 << 20));
  float*    bias_eff = (float*)   (ws + (2 << 20));
  float*    part     = (float*)   (ws + (4 << 20));

  const size_t need = (size_t)(4 << 20) + 2ull * 16384 * 256 * 4;
  const bool split = ws_size >= need;

  prep<<<dim3(1040), dim3(256), 0, stream>>>(w_inp, pbias, W_mid, b_mid, W_root, Wtm, Wtr, bias_eff);
  if (split) {
    fused<true><<<dim3(1024), dim3(256), 0, stream>>>(x, Wtm, Wtr, bias_eff, b_root, part);
    reducek<<<dim3(4096), dim3(256), 0, stream>>>(part, b_root, out);
  } else {
    fused<false><<<dim3(512), dim3(256), 0, stream>>>(x, Wtm, Wtr, bias_eff, b_root, out);
  }
}

// Round 2
// 398.723 us; speedup vs baseline: 1.1322x; 1.1264x over previous
//
#include <hip/hip_runtime.h>

typedef __attribute__((ext_vector_type(8))) short short8;
typedef __attribute__((ext_vector_type(4))) float floatx4;
typedef unsigned short ushort_t;
typedef unsigned int uint32;

// ---------- helpers ----------

__device__ __forceinline__ uint32 f2bf_bits(float f) {
  uint32 u = __builtin_bit_cast(uint32, f);
  u += 0x7fffu + ((u >> 16) & 1u);   // round-to-nearest-even
  return u >> 16;
}

__device__ __forceinline__ float tanh_fast(float x) {
  float e = __expf(2.0f * x);
  return 1.0f - 2.0f * __builtin_amdgcn_rcpf(e + 1.0f);
}

#define MFMA16(a, b, c) __builtin_amdgcn_mfma_f32_16x16x32_bf16((a), (b), (c), 0, 0, 0)

// lgkm-only barrier: __syncthreads() drains vmcnt(0) (kills in-flight HBM/L2
// prefetch every group). All cross-wave dataflow here is via LDS, so
// lgkmcnt(0) + s_barrier is sufficient for correctness.
#define BAR_LGKM() asm volatile("s_waitcnt lgkmcnt(0)\n\ts_barrier" ::: "memory")

// ---------- prep: fold weights, cast bf16, emit FRAGMENT-MAJOR layouts ----------
// v3: weights stored in per-wave MFMA fragment order so every B-frag load in
// `fused` is a contiguous 1 KB wave-load (lane*16B). The old [n][k] layout made
// each load a 16-line gather with 512B/4KB lane strides -> L2 channel camping
// (observed: per-block-group time scales with resident blocks, all pipes idle).
//
// Wtm2 panels: p = (g*8 + nb)*8 + kk          (nb: n-tile of 16, kk: k-chunk of 32)
//   offset kh*128 + l15*8 + e  <-  W_mid[g][i][o]*w_inp[g][i],
//   o = nb*16 + l15, i = kk*32 + kh*8 + e     (512 ushorts = 1 KB per panel)
// Wtr2 panels: q = (g*16 + nb)*4 + kk2
//   offset kh*128 + l15*8 + e  <-  W_root[k][o],
//   o = nb*16 + l15, k = g*128 + kk2*32 + kh*8 + e
//
// ws layout: Wtm2 1MB @0 | Wtr2 1MB @1MB | bias_eff @2MB | part @4MB

__global__ __launch_bounds__(256) void prep(const float* __restrict__ w_inp,
                                            const float* __restrict__ pbias,
                                            const float* __restrict__ W_mid,
                                            const float* __restrict__ b_mid,
                                            const float* __restrict__ W_root,
                                            ushort_t* __restrict__ Wtm2,
                                            ushort_t* __restrict__ Wtr2,
                                            float* __restrict__ bias_eff) {
  __shared__ float tl[32][33];
  __shared__ float red[256];
  const int b = blockIdx.x, t = threadIdx.x;
  const int tx = t & 31, ty = t >> 5;              // load-phase coords

  if (b < 512) {
    // per-g 256(i) x 128(o), 32x32 tiles: coalesced load+fold, frag-major store
    const int g = b >> 5, tile = b & 31;
    const int i0 = (tile >> 2) * 32, o0 = (tile & 3) * 32;
#pragma unroll
    for (int r = 0; r < 4; ++r) {
      const int il = ty * 4 + r;
      tl[il][tx] = W_mid[(g << 15) + (i0 + il) * 128 + o0 + tx] * w_inp[g * 256 + i0 + il];
    }
    __syncthreads();
    const int nl = t >> 3, s = t & 7;              // store-phase coords
    const int o = o0 + nl, nb = o >> 4, l15 = o & 15;
    const int kk = i0 >> 5;                        // i0 is 32-aligned
    const int iloc = s * 4, kh = iloc >> 3, e0 = iloc & 7;
    const uint32 lo = (uint32)f2bf_bits(tl[iloc + 0][nl]) |
                      ((uint32)f2bf_bits(tl[iloc + 1][nl]) << 16);
    const uint32 hi = (uint32)f2bf_bits(tl[iloc + 2][nl]) |
                      ((uint32)f2bf_bits(tl[iloc + 3][nl]) << 16);
    uint2* dst = (uint2*)(Wtm2 + (size_t)(((g * 8 + nb) * 8 + kk) * 512 + kh * 128 + l15 * 8 + e0));
    *dst = make_uint2(lo, hi);
  } else if (b < 1024) {
    // 2048(k) x 256(o), 32x32 tiles
    const int bb = b - 512;
    const int k0 = (bb >> 3) * 32, o0 = (bb & 7) * 32;
#pragma unroll
    for (int r = 0; r < 4; ++r) {
      const int kl = ty * 4 + r;
      tl[kl][tx] = W_root[(k0 + kl) * 256 + o0 + tx];
    }
    __syncthreads();
    const int nl = t >> 3, s = t & 7;
    const int o = o0 + nl, nb = o >> 4, l15 = o & 15;
    const int g = k0 >> 7, kk2 = (k0 >> 5) & 3;    // k0 is 32-aligned
    const int iloc = s * 4, kh = iloc >> 3, e0 = iloc & 7;
    const uint32 lo = (uint32)f2bf_bits(tl[iloc + 0][nl]) |
                      ((uint32)f2bf_bits(tl[iloc + 1][nl]) << 16);
    const uint32 hi = (uint32)f2bf_bits(tl[iloc + 2][nl]) |
                      ((uint32)f2bf_bits(tl[iloc + 3][nl]) << 16);
    uint2* dst = (uint2*)(Wtr2 + (size_t)(((g * 16 + nb) * 4 + kk2) * 512 + kh * 128 + l15 * 8 + e0));
    *dst = make_uint2(lo, hi);
  } else {
    // bias_eff[g][o] = b_mid[g][o] + sum_i pbias[g*4 + i>>6] * W_mid[g][i][o]
    const int g = b - 1024;
    const int o = t & 127, ih = t >> 7;
    const float* wp = W_mid + (g << 15) + ih * 128 * 128 + o;
    const float pb0 = pbias[g * 4 + ih * 2];
    const float pb1 = pbias[g * 4 + ih * 2 + 1];
    float s = 0.f;
#pragma unroll 8
    for (int ii = 0; ii < 128; ++ii) s += (ii < 64 ? pb0 : pb1) * wp[ii * 128];
    red[t] = s;
    __syncthreads();
    if (ih == 0) bias_eff[g * 128 + o] = b_mid[g * 128 + o] + red[o] + red[128 + o];
  }
}

// ---------- fused mid+root ----------
// Block: 256 threads (4 waves), 32 batch rows.
// SPLIT: grid 1024, each block does 8 groups (half-K), partials -> ws.
// All weight loads are contiguous 1 KB wave-loads from the fragment-major
// arrays (lane*16B); per-group body keeps the issue-order discipline:
// weights first, x prefetch last, 2 lgkm-only barriers.

template <bool SPLIT>
__global__ __launch_bounds__(256, 3) void fused(const float* __restrict__ x,
                                                const ushort_t* __restrict__ Wtm2,
                                                const ushort_t* __restrict__ Wtr2,
                                                const float* __restrict__ bias_eff,
                                                const float* __restrict__ b_root,
                                                float* __restrict__ dst) {
  constexpr int GROUPS = SPLIT ? 8 : 16;

  __shared__ __align__(16) ushort_t sX[32 * 264];   // stride 264: 16B rows, 2-way banks max
  __shared__ __align__(16) ushort_t sMid[32 * 136];

  const int t = threadIdx.x;
  const int lane = t & 63;
  const int wv = __builtin_amdgcn_readfirstlane(t >> 6);
  const int tile = SPLIT ? (int)(blockIdx.x >> 1) : (int)blockIdx.x;
  const int h = SPLIT ? (int)(blockIdx.x & 1) : 0;
  const int G0 = h * 8;
  const int m0 = tile * 32;
  const int l15 = lane & 15;
  const int kh = lane >> 4;          // 0..3

  // x staging: thread t handles row xr = t>>3, float4-slot xq = t&7 (+8 per pass)
  const int xr = t >> 3, xq = t & 7;
  const float* xbase = x + (size_t)(m0 + xr) * 4096 + (size_t)G0 * 256 + xq * 4;
  uint32* sxw = (uint32*)(sX + xr * 264 + xq * 4);

  // A-frag LDS read pointers
  const ushort_t* sxa0 = sX + l15 * 264 + kh * 8;
  const ushort_t* sxa1 = sX + (16 + l15) * 264 + kh * 8;
  const ushort_t* sma0 = sMid + l15 * 136 + kh * 8;
  const ushort_t* sma1 = sMid + (16 + l15) * 136 + kh * 8;

  // fragment-major weight bases: every load below = base + const -> 1 KB contiguous
  // Wtm2: group stride 1<<15 ushorts; wave's two n-panels at wv*2, wv*2+1 (4096 apart)
  const ushort_t* wtm_base = Wtm2 + (((size_t)G0) << 15) + (size_t)wv * (2 * 8 * 512) + (size_t)lane * 8;
  // Wtr2: group stride 1<<15 ushorts; wave's four n-panels at wv*4+ni
  const ushort_t* wtr_base = Wtr2 + (((size_t)G0) << 15) + (size_t)wv * (4 * 4 * 512) + (size_t)lane * 8;

  float4 rx[8];
  floatx4 racc[2][4] = {};

  // prologue: x for local group 0
#pragma unroll
  for (int p = 0; p < 8; ++p) rx[p] = *(const float4*)(xbase + p * 32);

#pragma unroll 1
  for (int g = 0; g < GROUPS; ++g) {
    // ---- body top: this group's first weight loads + biases ----
    const ushort_t* wb0 = wtm_base + ((size_t)g << 15);
    const ushort_t* wb1 = wb0 + 4096;
    short8 mb[2][2];
    mb[0][0] = *(const short8*)(wb0);
    mb[0][1] = *(const short8*)(wb1);
    mb[1][0] = *(const short8*)(wb0 + 512);
    mb[1][1] = *(const short8*)(wb1 + 512);
    const float bias0 = bias_eff[(G0 + g) * 128 + wv * 32 + l15];
    const float bias1 = bias_eff[(G0 + g) * 128 + wv * 32 + 16 + l15];

    // ---- convert rx (group g) -> sX, round-half-up + byte-perm pack ----
#pragma unroll
    for (int p = 0; p < 8; ++p) {
      uint32 bx = __builtin_bit_cast(uint32, rx[p].x) + 0x8000u;
      uint32 by = __builtin_bit_cast(uint32, rx[p].y) + 0x8000u;
      uint32 bz = __builtin_bit_cast(uint32, rx[p].z) + 0x8000u;
      uint32 bw = __builtin_bit_cast(uint32, rx[p].w) + 0x8000u;
      uint32 lo = __builtin_amdgcn_perm(by, bx, 0x07060302u);
      uint32 hi = __builtin_amdgcn_perm(bw, bz, 0x07060302u);
      *(uint2*)(sxw + p * 16) = make_uint2(lo, hi);
    }

    BAR_LGKM();  // (B) sX ready; also: all waves past root(g-1) -> sMid WAR safe

    // ---- mid GEMM: 32x128 (wave: 32m x 32n), K=256 ----
    floatx4 macc[2][2] = {};
#pragma unroll
    for (int kk = 0; kk < 8; ++kk) {
      short8 a0 = *(const short8*)(sxa0 + kk * 32);
      short8 a1 = *(const short8*)(sxa1 + kk * 32);
      short8 b0 = mb[kk & 1][0], b1 = mb[kk & 1][1];
      if (kk < 6) {  // no dead tail loads
        mb[kk & 1][0] = *(const short8*)(wb0 + (kk + 2) * 512);
        mb[kk & 1][1] = *(const short8*)(wb1 + (kk + 2) * 512);
      }
      macc[0][0] = MFMA16(a0, b0, macc[0][0]);
      macc[0][1] = MFMA16(a0, b1, macc[0][1]);
      macc[1][0] = MFMA16(a1, b0, macc[1][0]);
      macc[1][1] = MFMA16(a1, b1, macc[1][1]);
    }

    // ---- root B rounds 0,1 preload (8 frags = 32 VGPR) ----
    const ushort_t* wb = wtr_base + ((size_t)g << 15);
    short8 rb[2][4];
#pragma unroll
    for (int ni = 0; ni < 4; ++ni) rb[0][ni] = *(const short8*)(wb + (ni * 4 + 0) * 512);
#pragma unroll
    for (int ni = 0; ni < 4; ++ni) rb[1][ni] = *(const short8*)(wb + (ni * 4 + 1) * 512);

    __builtin_amdgcn_sched_barrier(0);  // pin: weights above issue before rx below

    // ---- prefetch next group's x (LAST vmem of the preload phase) ----
    if (g < GROUPS - 1) {
      const float* xn = xbase + (g + 1) * 256;
#pragma unroll
      for (int p = 0; p < 8; ++p) rx[p] = *(const float4*)(xn + p * 32);
    }

    __builtin_amdgcn_sched_barrier(0);  // keep rx issue here (not sunk past epilogue)

    // ---- epilogue: bias + tanh -> sMid (bf16, root-A layout) ----
#pragma unroll
    for (int ni = 0; ni < 2; ++ni) {
      const float bias = ni ? bias1 : bias0;
      const int col = wv * 32 + ni * 16 + l15;
#pragma unroll
      for (int mi = 0; mi < 2; ++mi)
#pragma unroll
        for (int r = 0; r < 4; ++r) {
          const int row = mi * 16 + kh * 4 + r;
          sMid[row * 136 + col] = (ushort_t)f2bf_bits(tanh_fast(macc[mi][ni][r] + bias));
        }
    }

    BAR_LGKM();  // (C) sMid ready

    // ---- root partial: 32x256 (wave: 32m x 64n), K=128, accumulate in racc ----
#pragma unroll
    for (int kk2 = 0; kk2 < 4; ++kk2) {
      short8 a0 = *(const short8*)(sma0 + kk2 * 32);
      short8 a1 = *(const short8*)(sma1 + kk2 * 32);
      short8 b0 = rb[kk2 & 1][0], b1 = rb[kk2 & 1][1];
      short8 b2 = rb[kk2 & 1][2], b3 = rb[kk2 & 1][3];
      if (kk2 < 2) {  // stream rounds 2,3; no dead tail loads
#pragma unroll
        for (int ni = 0; ni < 4; ++ni)
          rb[kk2 & 1][ni] = *(const short8*)(wb + (ni * 4 + kk2 + 2) * 512);
      }
      racc[0][0] = MFMA16(a0, b0, racc[0][0]);
      racc[0][1] = MFMA16(a0, b1, racc[0][1]);
      racc[0][2] = MFMA16(a0, b2, racc[0][2]);
      racc[0][3] = MFMA16(a0, b3, racc[0][3]);
      racc[1][0] = MFMA16(a1, b0, racc[1][0]);
      racc[1][1] = MFMA16(a1, b1, racc[1][1]);
      racc[1][2] = MFMA16(a1, b2, racc[1][2]);
      racc[1][3] = MFMA16(a1, b3, racc[1][3]);
    }
  }

  // ---- final store ----
  float* o = SPLIT ? dst + (size_t)h * (16384 * 256) : dst;
#pragma unroll
  for (int ni = 0; ni < 4; ++ni) {
    const int col = wv * 64 + ni * 16 + l15;
    const float br = SPLIT ? 0.0f : b_root[col];
#pragma unroll
    for (int mi = 0; mi < 2; ++mi)
#pragma unroll
      for (int r = 0; r < 4; ++r) {
        const int row = m0 + mi * 16 + kh * 4 + r;
        o[(size_t)row * 256 + col] = racc[mi][ni][r] + br;
      }
  }
}

// ---------- split-K reduce: out = p0 + p1 + b_root ----------

__global__ __launch_bounds__(256) void reducek(const float* __restrict__ part,
                                               const float* __restrict__ b_root,
                                               float* __restrict__ out) {
  const int i = blockIdx.x * 256 + threadIdx.x;   // float4 index, 1,048,576 total
  float4 a = ((const float4*)part)[i];
  float4 c = ((const float4*)(part + (size_t)16384 * 256))[i];
  float4 br = ((const float4*)b_root)[i & 63];
  float4 r;
  r.x = a.x + c.x + br.x;
  r.y = a.y + c.y + br.y;
  r.z = a.z + c.z + br.z;
  r.w = a.w + c.w + br.w;
  ((float4*)out)[i] = r;
}

// ---------- launch ----------

extern "C" void kernel_launch(void* const* d_in, const int* in_sizes, int n_in,
                              void* d_out, int out_size, void* d_ws, size_t ws_size,
                              hipStream_t stream) {
  const float* x      = (const float*)d_in[0];
  const float* w_inp  = (const float*)d_in[1];
  const float* pbias  = (const float*)d_in[2];
  const float* W_mid  = (const float*)d_in[3];
  const float* b_mid  = (const float*)d_in[4];
  const float* W_root = (const float*)d_in[5];
  const float* b_root = (const float*)d_in[6];
  float* out = (float*)d_out;

  char* ws = (char*)d_ws;
  ushort_t* Wtm2     = (ushort_t*)(ws);
  ushort_t* Wtr2     = (ushort_t*)(ws + (1 << 20));
  float*    bias_eff = (float*)   (ws + (2 << 20));
  float*    part     = (float*)   (ws + (4 << 20));

  const size_t need = (size_t)(4 << 20) + 2ull * 16384 * 256 * 4;
  const bool split = ws_size >= need;

  prep<<<dim3(1040), dim3(256), 0, stream>>>(w_inp, pbias, W_mid, b_mid, W_root, Wtm2, Wtr2, bias_eff);
  if (split) {
    fused<true><<<dim3(1024), dim3(256), 0, stream>>>(x, Wtm2, Wtr2, bias_eff, b_root, part);
    reducek<<<dim3(4096), dim3(256), 0, stream>>>(part, b_root, out);
  } else {
    fused<false><<<dim3(512), dim3(256), 0, stream>>>(x, Wtm2, Wtr2, bias_eff, b_root, out);
  }
}

// Round 3
// 388.533 us; speedup vs baseline: 1.1619x; 1.0262x over previous
//
#include <hip/hip_runtime.h>

typedef __attribute__((ext_vector_type(8))) short short8;
typedef __attribute__((ext_vector_type(4))) float floatx4;
typedef unsigned short ushort_t;
typedef unsigned int uint32;

// ---------- helpers ----------

__device__ __forceinline__ uint32 f2bf_bits(float f) {
  uint32 u = __builtin_bit_cast(uint32, f);
  u += 0x7fffu + ((u >> 16) & 1u);   // round-to-nearest-even
  return u >> 16;
}

__device__ __forceinline__ float tanh_fast(float x) {
  float e = __expf(2.0f * x);
  return 1.0f - 2.0f * __builtin_amdgcn_rcpf(e + 1.0f);
}

#define MFMA16(a, b, c) __builtin_amdgcn_mfma_f32_16x16x32_bf16((a), (b), (c), 0, 0, 0)

// lgkm-only barrier: __syncthreads() drains vmcnt(0) (kills in-flight HBM/L2
// prefetch every group). All cross-wave dataflow here is via LDS, so
// lgkmcnt(0) + s_barrier is sufficient for correctness.
#define BAR_LGKM() asm volatile("s_waitcnt lgkmcnt(0)\n\ts_barrier" ::: "memory")

// ---------- prep: fold weights, cast bf16, emit FRAGMENT-MAJOR layouts ----------
// (unchanged from v3 — layouts are consumption-agnostic)
// Wtm2 panels: p = (g*8 + nb)*8 + kk          (nb: n-tile of 16, kk: k-chunk of 32)
//   offset kh*128 + l15*8 + e  <-  W_mid[g][i][o]*w_inp[g][i],
//   o = nb*16 + l15, i = kk*32 + kh*8 + e     (512 ushorts = 1 KB per panel)
// Wtr2 panels: q = (g*16 + nb)*4 + kk2
//   offset kh*128 + l15*8 + e  <-  W_root[k][o],
//   o = nb*16 + l15, k = g*128 + kk2*32 + kh*8 + e
//
// ws layout: Wtm2 1MB @0 | Wtr2 1MB @1MB | bias_eff @2MB | part @4MB

__global__ __launch_bounds__(256) void prep(const float* __restrict__ w_inp,
                                            const float* __restrict__ pbias,
                                            const float* __restrict__ W_mid,
                                            const float* __restrict__ b_mid,
                                            const float* __restrict__ W_root,
                                            ushort_t* __restrict__ Wtm2,
                                            ushort_t* __restrict__ Wtr2,
                                            float* __restrict__ bias_eff) {
  __shared__ float tl[32][33];
  __shared__ float red[256];
  const int b = blockIdx.x, t = threadIdx.x;
  const int tx = t & 31, ty = t >> 5;              // load-phase coords

  if (b < 512) {
    // per-g 256(i) x 128(o), 32x32 tiles: coalesced load+fold, frag-major store
    const int g = b >> 5, tile = b & 31;
    const int i0 = (tile >> 2) * 32, o0 = (tile & 3) * 32;
#pragma unroll
    for (int r = 0; r < 4; ++r) {
      const int il = ty * 4 + r;
      tl[il][tx] = W_mid[(g << 15) + (i0 + il) * 128 + o0 + tx] * w_inp[g * 256 + i0 + il];
    }
    __syncthreads();
    const int nl = t >> 3, s = t & 7;              // store-phase coords
    const int o = o0 + nl, nb = o >> 4, l15 = o & 15;
    const int kk = i0 >> 5;                        // i0 is 32-aligned
    const int iloc = s * 4, kh = iloc >> 3, e0 = iloc & 7;
    const uint32 lo = (uint32)f2bf_bits(tl[iloc + 0][nl]) |
                      ((uint32)f2bf_bits(tl[iloc + 1][nl]) << 16);
    const uint32 hi = (uint32)f2bf_bits(tl[iloc + 2][nl]) |
                      ((uint32)f2bf_bits(tl[iloc + 3][nl]) << 16);
    uint2* dst = (uint2*)(Wtm2 + (size_t)(((g * 8 + nb) * 8 + kk) * 512 + kh * 128 + l15 * 8 + e0));
    *dst = make_uint2(lo, hi);
  } else if (b < 1024) {
    // 2048(k) x 256(o), 32x32 tiles
    const int bb = b - 512;
    const int k0 = (bb >> 3) * 32, o0 = (bb & 7) * 32;
#pragma unroll
    for (int r = 0; r < 4; ++r) {
      const int kl = ty * 4 + r;
      tl[kl][tx] = W_root[(k0 + kl) * 256 + o0 + tx];
    }
    __syncthreads();
    const int nl = t >> 3, s = t & 7;
    const int o = o0 + nl, nb = o >> 4, l15 = o & 15;
    const int g = k0 >> 7, kk2 = (k0 >> 5) & 3;    // k0 is 32-aligned
    const int iloc = s * 4, kh = iloc >> 3, e0 = iloc & 7;
    const uint32 lo = (uint32)f2bf_bits(tl[iloc + 0][nl]) |
                      ((uint32)f2bf_bits(tl[iloc + 1][nl]) << 16);
    const uint32 hi = (uint32)f2bf_bits(tl[iloc + 2][nl]) |
                      ((uint32)f2bf_bits(tl[iloc + 3][nl]) << 16);
    uint2* dst = (uint2*)(Wtr2 + (size_t)(((g * 16 + nb) * 4 + kk2) * 512 + kh * 128 + l15 * 8 + e0));
    *dst = make_uint2(lo, hi);
  } else {
    // bias_eff[g][o] = b_mid[g][o] + sum_i pbias[g*4 + i>>6] * W_mid[g][i][o]
    const int g = b - 1024;
    const int o = t & 127, ih = t >> 7;
    const float* wp = W_mid + (g << 15) + ih * 128 * 128 + o;
    const float pb0 = pbias[g * 4 + ih * 2];
    const float pb1 = pbias[g * 4 + ih * 2 + 1];
    float s = 0.f;
#pragma unroll 8
    for (int ii = 0; ii < 128; ++ii) s += (ii < 64 ? pb0 : pb1) * wp[ii * 128];
    red[t] = s;
    __syncthreads();
    if (ih == 0) bias_eff[g * 128 + o] = b_mid[g * 128 + o] + red[o] + red[128 + o];
  }
}

// ---------- fused mid+root ----------
// v4: M=64 rows/block, 8 waves (512 threads), split-K x2 -> grid 512 (2 blocks/CU).
// Halves per-group weight re-streaming from L2 (1 GB -> 512 MB total) and raises
// waves/CU 10->16. Wave w: mid n-slice = 16 cols (panel nb=w), root n-slice =
// 32 cols (panels nb=w*2, w*2+1). Same fragment-major 1 KB wave-loads, same
// lgkm-only barriers, same issue-order discipline (weights first, x last).

template <bool SPLIT>
__global__ __launch_bounds__(512, 4) void fused(const float* __restrict__ x,
                                                const ushort_t* __restrict__ Wtm2,
                                                const ushort_t* __restrict__ Wtr2,
                                                const float* __restrict__ bias_eff,
                                                const float* __restrict__ b_root,
                                                float* __restrict__ dst) {
  constexpr int GROUPS = SPLIT ? 8 : 16;

  __shared__ __align__(16) ushort_t sX[64 * 264];   // 33.8 KB
  __shared__ __align__(16) ushort_t sMid[64 * 136]; // 17.4 KB

  const int t = threadIdx.x;
  const int lane = t & 63;
  const int w = __builtin_amdgcn_readfirstlane(t >> 6);   // wave 0..7
  const int tile = SPLIT ? (int)(blockIdx.x >> 1) : (int)blockIdx.x;
  const int h = SPLIT ? (int)(blockIdx.x & 1) : 0;
  const int G0 = h * 8;
  const int m0 = tile * 64;
  const int l15 = lane & 15;
  const int kh = lane >> 4;          // 0..3

  // x staging: thread t handles row xr = t>>3 (0..63), float4-slot xq = t&7
  const int xr = t >> 3, xq = t & 7;
  const float* xbase = x + (size_t)(m0 + xr) * 4096 + (size_t)G0 * 256 + xq * 4;
  uint32* sxw = (uint32*)(sX + xr * 264 + xq * 4);

  // A-frag LDS read pointers (4 row-frags each)
  const ushort_t* sxa[4];
  const ushort_t* sma[4];
#pragma unroll
  for (int af = 0; af < 4; ++af) {
    sxa[af] = sX + (af * 16 + l15) * 264 + kh * 8;
    sma[af] = sMid + (af * 16 + l15) * 136 + kh * 8;
  }

  // fragment-major weight bases: every load below = base + const -> 1 KB contiguous
  const ushort_t* wtm_base = Wtm2 + (((size_t)G0) << 15) + (size_t)w * (8 * 512) + (size_t)lane * 8;
  const ushort_t* wtr_base = Wtr2 + (((size_t)G0) << 15) + (size_t)w * (2 * 4 * 512) + (size_t)lane * 8;

  float4 rx[8];
  floatx4 racc[4][2] = {};

  // prologue: x for local group 0
#pragma unroll
  for (int p = 0; p < 8; ++p) rx[p] = *(const float4*)(xbase + p * 32);

#pragma unroll 1
  for (int g = 0; g < GROUPS; ++g) {
    // ---- body top: this group's first weight loads + bias ----
    const ushort_t* wb0 = wtm_base + ((size_t)g << 15);
    short8 mb[2];
    mb[0] = *(const short8*)(wb0);
    mb[1] = *(const short8*)(wb0 + 512);
    const float bias = bias_eff[(G0 + g) * 128 + w * 16 + l15];

    // ---- convert rx (group g) -> sX, round-half-up + byte-perm pack ----
#pragma unroll
    for (int p = 0; p < 8; ++p) {
      uint32 bx = __builtin_bit_cast(uint32, rx[p].x) + 0x8000u;
      uint32 by = __builtin_bit_cast(uint32, rx[p].y) + 0x8000u;
      uint32 bz = __builtin_bit_cast(uint32, rx[p].z) + 0x8000u;
      uint32 bw = __builtin_bit_cast(uint32, rx[p].w) + 0x8000u;
      uint32 lo = __builtin_amdgcn_perm(by, bx, 0x07060302u);
      uint32 hi = __builtin_amdgcn_perm(bw, bz, 0x07060302u);
      *(uint2*)(sxw + p * 16) = make_uint2(lo, hi);
    }

    BAR_LGKM();  // (B) sX ready; also: all waves past root(g-1) -> sMid WAR safe

    // ---- mid GEMM: 64x16 per wave (4 row-frags x 1 n-frag), K=256 ----
    floatx4 macc[4] = {};
#pragma unroll
    for (int kk = 0; kk < 8; ++kk) {
      short8 a0 = *(const short8*)(sxa[0] + kk * 32);
      short8 a1 = *(const short8*)(sxa[1] + kk * 32);
      short8 a2 = *(const short8*)(sxa[2] + kk * 32);
      short8 a3 = *(const short8*)(sxa[3] + kk * 32);
      short8 b = mb[kk & 1];
      if (kk < 6) mb[kk & 1] = *(const short8*)(wb0 + (kk + 2) * 512);
      macc[0] = MFMA16(a0, b, macc[0]);
      macc[1] = MFMA16(a1, b, macc[1]);
      macc[2] = MFMA16(a2, b, macc[2]);
      macc[3] = MFMA16(a3, b, macc[3]);
    }

    // ---- root B rounds 0,1 preload (4 frags) ----
    const ushort_t* wb = wtr_base + ((size_t)g << 15);
    short8 rb[2][2];
#pragma unroll
    for (int ni = 0; ni < 2; ++ni) rb[0][ni] = *(const short8*)(wb + (ni * 4 + 0) * 512);
#pragma unroll
    for (int ni = 0; ni < 2; ++ni) rb[1][ni] = *(const short8*)(wb + (ni * 4 + 1) * 512);

    __builtin_amdgcn_sched_barrier(0);  // pin: weights above issue before rx below

    // ---- prefetch next group's x (LAST vmem of the preload phase) ----
    if (g < GROUPS - 1) {
      const float* xn = xbase + (g + 1) * 256;
#pragma unroll
      for (int p = 0; p < 8; ++p) rx[p] = *(const float4*)(xn + p * 32);
    }

    __builtin_amdgcn_sched_barrier(0);  // keep rx issue here (not sunk past epilogue)

    // ---- epilogue: bias + tanh -> sMid (bf16, root-A layout) ----
    {
      const int col = w * 16 + l15;
#pragma unroll
      for (int af = 0; af < 4; ++af)
#pragma unroll
        for (int r = 0; r < 4; ++r) {
          const int row = af * 16 + kh * 4 + r;
          sMid[row * 136 + col] = (ushort_t)f2bf_bits(tanh_fast(macc[af][r] + bias));
        }
    }

    BAR_LGKM();  // (C) sMid ready

    // ---- root partial: 64x32 per wave (4 row-frags x 2 n-frags), K=128 ----
#pragma unroll
    for (int kk2 = 0; kk2 < 4; ++kk2) {
      short8 a0 = *(const short8*)(sma[0] + kk2 * 32);
      short8 a1 = *(const short8*)(sma[1] + kk2 * 32);
      short8 a2 = *(const short8*)(sma[2] + kk2 * 32);
      short8 a3 = *(const short8*)(sma[3] + kk2 * 32);
      short8 b0 = rb[kk2 & 1][0], b1 = rb[kk2 & 1][1];
      if (kk2 < 2) {  // stream rounds 2,3; no dead tail loads
#pragma unroll
        for (int ni = 0; ni < 2; ++ni)
          rb[kk2 & 1][ni] = *(const short8*)(wb + (ni * 4 + kk2 + 2) * 512);
      }
      racc[0][0] = MFMA16(a0, b0, racc[0][0]);
      racc[0][1] = MFMA16(a0, b1, racc[0][1]);
      racc[1][0] = MFMA16(a1, b0, racc[1][0]);
      racc[1][1] = MFMA16(a1, b1, racc[1][1]);
      racc[2][0] = MFMA16(a2, b0, racc[2][0]);
      racc[2][1] = MFMA16(a2, b1, racc[2][1]);
      racc[3][0] = MFMA16(a3, b0, racc[3][0]);
      racc[3][1] = MFMA16(a3, b1, racc[3][1]);
    }
  }

  // ---- final store ----
  float* o = SPLIT ? dst + (size_t)h * (16384 * 256) : dst;
#pragma unroll
  for (int ni = 0; ni < 2; ++ni) {
    const int col = w * 32 + ni * 16 + l15;
    const float br = SPLIT ? 0.0f : b_root[col];
#pragma unroll
    for (int af = 0; af < 4; ++af)
#pragma unroll
      for (int r = 0; r < 4; ++r) {
        const int row = m0 + af * 16 + kh * 4 + r;
        o[(size_t)row * 256 + col] = racc[af][ni][r] + br;
      }
  }
}

// ---------- split-K reduce: out = p0 + p1 + b_root ----------

__global__ __launch_bounds__(256) void reducek(const float* __restrict__ part,
                                               const float* __restrict__ b_root,
                                               float* __restrict__ out) {
  const int i = blockIdx.x * 256 + threadIdx.x;   // float4 index, 1,048,576 total
  float4 a = ((const float4*)part)[i];
  float4 c = ((const float4*)(part + (size_t)16384 * 256))[i];
  float4 br = ((const float4*)b_root)[i & 63];
  float4 r;
  r.x = a.x + c.x + br.x;
  r.y = a.y + c.y + br.y;
  r.z = a.z + c.z + br.z;
  r.w = a.w + c.w + br.w;
  ((float4*)out)[i] = r;
}

// ---------- launch ----------

extern "C" void kernel_launch(void* const* d_in, const int* in_sizes, int n_in,
                              void* d_out, int out_size, void* d_ws, size_t ws_size,
                              hipStream_t stream) {
  const float* x      = (const float*)d_in[0];
  const float* w_inp  = (const float*)d_in[1];
  const float* pbias  = (const float*)d_in[2];
  const float* W_mid  = (const float*)d_in[3];
  const float* b_mid  = (const float*)d_in[4];
  const float* W_root = (const float*)d_in[5];
  const float* b_root = (const float*)d_in[6];
  float* out = (float*)d_out;

  char* ws = (char*)d_ws;
  ushort_t* Wtm2     = (ushort_t*)(ws);
  ushort_t* Wtr2     = (ushort_t*)(ws + (1 << 20));
  float*    bias_eff = (float*)   (ws + (2 << 20));
  float*    part     = (float*)   (ws + (4 << 20));

  const size_t need = (size_t)(4 << 20) + 2ull * 16384 * 256 * 4;
  const bool split = ws_size >= need;

  prep<<<dim3(1040), dim3(256), 0, stream>>>(w_inp, pbias, W_mid, b_mid, W_root, Wtm2, Wtr2, bias_eff);
  if (split) {
    fused<true><<<dim3(512), dim3(512), 0, stream>>>(x, Wtm2, Wtr2, bias_eff, b_root, part);
    reducek<<<dim3(4096), dim3(256), 0, stream>>>(part, b_root, out);
  } else {
    fused<false><<<dim3(256), dim3(512), 0, stream>>>(x, Wtm2, Wtr2, bias_eff, b_root, out);
  }
}